// Round 1
// baseline (144.183 us; speedup 1.0000x reference)
//
#include <hip/hip_runtime.h>
#include <cstdint>
#include <cstddef>

#define THETA 1.2f
#define XI 0.3f
#define BDIM 8192
#define DDIM 512

typedef __bf16 bf16x8 __attribute__((ext_vector_type(8)));
typedef float f32x4 __attribute__((ext_vector_type(4)));

__device__ inline unsigned short f2bf(float f) {
    union { float f; unsigned int u; } a; a.f = f;
    unsigned int r = a.u + 0x7fffu + ((a.u >> 16) & 1u);  // RN-even
    return (unsigned short)(r >> 16);
}

// Kernel 1: per-row L2 normalize fp32 -> bf16 bits, emit sq[row] = ||n||^2 (~1), zero acc.
// One wave per row, 4 rows per 256-thread block.
__global__ __launch_bounds__(256) void normalize_rows(
    const float* __restrict__ x, unsigned short* __restrict__ nbf,
    float* __restrict__ sq, double* __restrict__ acc)
{
    if (blockIdx.x == 0 && threadIdx.x == 0) *acc = 0.0;
    int row = blockIdx.x * 4 + (threadIdx.x >> 6);
    int l = threadIdx.x & 63;
    const float4* xr = (const float4*)(x + (size_t)row * DDIM);
    float4 v0 = xr[l];        // cols 4l .. 4l+3
    float4 v1 = xr[l + 64];   // cols 256+4l .. +3
    float s = v0.x*v0.x + v0.y*v0.y + v0.z*v0.z + v0.w*v0.w
            + v1.x*v1.x + v1.y*v1.y + v1.z*v1.z + v1.w*v1.w;
    #pragma unroll
    for (int m = 1; m < 64; m <<= 1) s += __shfl_xor(s, m);
    float rn = rsqrtf(s);
    ushort4 o0, o1;
    o0.x = f2bf(v0.x * rn); o0.y = f2bf(v0.y * rn);
    o0.z = f2bf(v0.z * rn); o0.w = f2bf(v0.w * rn);
    o1.x = f2bf(v1.x * rn); o1.y = f2bf(v1.y * rn);
    o1.z = f2bf(v1.z * rn); o1.w = f2bf(v1.w * rn);
    ushort4* nr = (ushort4*)(nbf + (size_t)row * DDIM);
    nr[l] = o0; nr[l + 64] = o1;
    if (l == 0) sq[row] = s * rn * rn;
}

// Kernel 2: upper-triangular 128x128 Gram tiles via 16x16x32 bf16 MFMA,
// fused hinge-loss reduction in the epilogue. Grid (64,64); bj<bi blocks exit.
__global__ __launch_bounds__(256) void gram_hinge(
    const unsigned short* __restrict__ nbf, const float* __restrict__ sq,
    const int* __restrict__ y, double* __restrict__ acc)
{
    int bi = blockIdx.x, bj = blockIdx.y;
    if (bj < bi) return;

    __shared__ unsigned short As[128 * 32];  // [tile_row][k], 8 KB
    __shared__ unsigned short Bs[128 * 32];
    __shared__ float wpart[4];

    int tid = threadIdx.x;
    int w = tid >> 6, l = tid & 63;
    int wr = w >> 1, wc = w & 1;     // wave 2x2 -> 64x64 subtile each
    int lr = l & 15, q = l >> 4;

    f32x4 accv[4][4] = {};

    const unsigned short* gA = nbf + (size_t)bi * 128 * DDIM;
    const unsigned short* gB = nbf + (size_t)bj * 128 * DDIM;
    int srow = l >> 2;            // 0..15 within chunk
    int scol = (l & 3) * 8;       // 0,8,16,24

    for (int k0 = 0; k0 < DDIM; k0 += 32) {
        __syncthreads();   // LDS reads of prev iter done (also drains vmcnt)
        #pragma unroll
        for (int c2 = 0; c2 < 2; ++c2) {
            int chunk = w + c2 * 4;              // wave-uniform, 0..7
            int r = chunk * 16 + srow;
            const unsigned short* ga = gA + (size_t)r * DDIM + k0 + scol;
            const unsigned short* gb = gB + (size_t)r * DDIM + k0 + scol;
            __builtin_amdgcn_global_load_lds(
                (const __attribute__((address_space(1))) void*)ga,
                (__attribute__((address_space(3))) void*)(As + chunk * 512), 16, 0, 0);
            __builtin_amdgcn_global_load_lds(
                (const __attribute__((address_space(1))) void*)gb,
                (__attribute__((address_space(3))) void*)(Bs + chunk * 512), 16, 0, 0);
        }
        __syncthreads();   // staging visible (compiler emits vmcnt(0) before barrier)

        const bf16x8* Av = (const bf16x8*)As;
        const bf16x8* Bv = (const bf16x8*)Bs;
        bf16x8 af[4], bfr[4];
        #pragma unroll
        for (int mi = 0; mi < 4; ++mi) af[mi]  = Av[(wr * 64 + mi * 16 + lr) * 4 + q];
        #pragma unroll
        for (int ni = 0; ni < 4; ++ni) bfr[ni] = Bv[(wc * 64 + ni * 16 + lr) * 4 + q];
        #pragma unroll
        for (int mi = 0; mi < 4; ++mi)
            #pragma unroll
            for (int ni = 0; ni < 4; ++ni)
                accv[mi][ni] = __builtin_amdgcn_mfma_f32_16x16x32_bf16(
                    af[mi], bfr[ni], accv[mi][ni], 0, 0, 0);
    }

    // Epilogue: C/D layout col=lane&15, row=q*4+reg (verified m89/m91).
    int jbase = bj * 128 + wc * 64 + lr;
    float sqj[4]; int yj[4];
    #pragma unroll
    for (int ni = 0; ni < 4; ++ni) {
        int gj = jbase + ni * 16;
        sqj[ni] = sq[gj]; yj[ni] = y[gj];
    }
    float local = 0.f;
    #pragma unroll
    for (int mi = 0; mi < 4; ++mi) {
        #pragma unroll
        for (int r = 0; r < 4; ++r) {
            int gi = bi * 128 + wr * 64 + mi * 16 + q * 4 + r;
            float sqi = sq[gi]; int yi = y[gi];
            #pragma unroll
            for (int ni = 0; ni < 4; ++ni) {
                int gj = jbase + ni * 16;
                float G = accv[mi][ni][r];
                float d2 = sqi + sqj[ni] - 2.0f * G;
                float h = fmaxf(THETA - d2, 0.0f);
                float t = XI + ((yi == yj[ni]) ? h : -h);
                if (gj >= gi) local += t;   // always true for bj>bi blocks
            }
        }
    }
    #pragma unroll
    for (int off = 32; off > 0; off >>= 1) local += __shfl_down(local, off);
    if (l == 0) wpart[w] = local;
    __syncthreads();
    if (tid == 0) {
        double ssum = (double)wpart[0] + (double)wpart[1]
                    + (double)wpart[2] + (double)wpart[3];
        atomicAdd(acc, ssum);
    }
}

__global__ void finalize(const double* __restrict__ acc, float* __restrict__ out) {
    const double m = 1.0 / ((double)BDIM * (double)BDIM - (double)BDIM);
    out[0] = (float)(*acc * m);
}

extern "C" void kernel_launch(void* const* d_in, const int* in_sizes, int n_in,
                              void* d_out, int out_size, void* d_ws, size_t ws_size,
                              hipStream_t stream) {
    const float* x = (const float*)d_in[0];
    const int* y = (const int*)d_in[1];
    float* out = (float*)d_out;

    unsigned short* nbf = (unsigned short*)d_ws;                       // 8 MB bf16 bits
    float* sq = (float*)((char*)d_ws + (size_t)BDIM * DDIM * 2);       // 32 KB
    double* acc = (double*)((char*)d_ws + (size_t)BDIM * DDIM * 2 + (size_t)BDIM * 4);

    normalize_rows<<<BDIM / 4, 256, 0, stream>>>(x, nbf, sq, acc);
    gram_hinge<<<dim3(64, 64), 256, 0, stream>>>(nbf, sq, y, acc);
    finalize<<<1, 1, 0, stream>>>(acc, out);
}